// Round 5
// baseline (391.493 us; speedup 1.0000x reference)
//
#include <hip/hip_runtime.h>
#include <math.h>

#define FIN 128
#define D1  256
#define D2  128
#define KCL 32
#define CAP 8192          // max edges per 256-node bin (avg ~4082, huge headroom)

typedef __attribute__((ext_vector_type(8))) short short8;
typedef __attribute__((ext_vector_type(4))) float floatx4;

__device__ __forceinline__ ushort f2bf(float f) {
    unsigned u = __float_as_uint(f);
    unsigned r = (u + 0x7fffu + ((u >> 16) & 1u)) >> 16;
    return (ushort)r;
}
__device__ __forceinline__ float bf2f(ushort h) {
    return __uint_as_float(((unsigned)h) << 16);
}

// ---------------- P1: bin-scatter edges (dir 0: by dst, dir 1: by src) ----------------
__global__ __launch_bounds__(256) void k_p1(const int* __restrict__ edges, int E, int NBIN,
                                            int* __restrict__ gcnt, unsigned* __restrict__ binbuf) {
    int dir = blockIdx.y;
    __shared__ int h[256], base[256], cur[256];
    int t = threadIdx.x;
    h[t] = 0;
    __syncthreads();
    int chunk = (E + gridDim.x - 1) / gridDim.x;
    int lo = blockIdx.x * chunk, hi = min(lo + chunk, E);
    const int* keys = dir ? edges : edges + E;
    for (int e = lo + t; e < hi; e += 256) atomicAdd(&h[keys[e] >> 8], 1);
    __syncthreads();
    if (t < NBIN) { base[t] = atomicAdd(&gcnt[dir * NBIN + t], h[t]); }
    cur[t] = 0;
    __syncthreads();
    unsigned* bb = binbuf + (size_t)dir * NBIN * CAP;
    for (int e = lo + t; e < hi; e += 256) {
        int r = edges[e], c = edges[E + e];
        int key = dir ? r : c;
        unsigned payload = dir ? ((unsigned)c | ((unsigned)(r & 255) << 16))
                               : ((unsigned)r | ((unsigned)(c & 255) << 16));
        int b = key >> 8;
        int pos = base[b] + atomicAdd(&cur[b], 1);
        if (pos < CAP) bb[(size_t)b * CAP + pos] = payload;
    }
}

// ---------------- P2: per-bin CSR build + degrees + dinv ----------------
__global__ __launch_bounds__(256) void k_p2(const unsigned* __restrict__ binbuf, const int* __restrict__ gcnt,
                                            int N, int E, int NBIN,
                                            int* __restrict__ col_ptr, int* __restrict__ row_ptr,
                                            ushort* __restrict__ col_idx, ushort* __restrict__ row_idx,
                                            float* __restrict__ dinv1, float* __restrict__ dinv2) {
    int d = blockIdx.y, b = blockIdx.x, t = threadIdx.x;
    __shared__ int sc[256], h[256], hx[256], cur[256];
    sc[t] = (t < NBIN) ? gcnt[d * NBIN + t] : 0;
    __syncthreads();
    for (int st = 1; st < 256; st <<= 1) {
        int u = (t >= st) ? sc[t - st] : 0;
        __syncthreads();
        sc[t] += u;
        __syncthreads();
    }
    int cnt_b = gcnt[d * NBIN + b];
    int binbase = sc[b] - cnt_b;
    h[t] = 0;
    __syncthreads();
    const unsigned* bb = binbuf + ((size_t)d * NBIN + b) * CAP;
    int m = min(cnt_b, CAP);
    for (int i = t; i < m; i += 256) atomicAdd(&h[bb[i] >> 16], 1);
    __syncthreads();
    int hv = h[t];
    hx[t] = hv;
    __syncthreads();
    for (int st = 1; st < 256; st <<= 1) {
        int u = (t >= st) ? hx[t - st] : 0;
        __syncthreads();
        hx[t] += u;
        __syncthreads();
    }
    int excl = hx[t] - hv;
    int node = b * 256 + t;
    if (node < N) {
        if (d == 0) {
            dinv1[node] = rsqrtf((float)hv + 1.0f);
            col_ptr[node] = binbase + excl;
            if (node == N - 1) col_ptr[N] = E;
        } else {
            dinv2[node] = hv ? rsqrtf((float)hv) : 0.0f;
            row_ptr[node] = binbase + excl;
            if (node == N - 1) row_ptr[N] = E;
        }
    }
    hx[t] = excl;
    cur[t] = 0;
    __syncthreads();
    ushort* oidx = d ? row_idx : col_idx;
    for (int i = t; i < m; i += 256) {
        unsigned p = bb[i];
        int nl = p >> 16;
        int rk = atomicAdd(&cur[nl], 1);
        oidx[binbase + hx[nl] + rk] = (ushort)(p & 0xffff);
    }
}

// ---------------- Xs = bf16(dinv1[j] * X[j]) ----------------
__global__ void k_cast(const float* __restrict__ X, const float* __restrict__ dinv1,
                       unsigned* __restrict__ Xs2, long n2) {
    long i = (long)blockIdx.x * blockDim.x + threadIdx.x;
    if (i < n2) {
        float2 v = ((const float2*)X)[i];
        float d = dinv1[i >> 6];                 // 64 uint-pairs per 128-col row
        Xs2[i] = (unsigned)f2bf(d * v.x) | ((unsigned)f2bf(d * v.y) << 16);
    }
}

// ---------------- v_j = dinv1[j]*(dinv1[j] + sum_{i in out(j)} dinv1[i]) ----------------
__global__ void k_v(const int* __restrict__ row_ptr, const ushort* __restrict__ row_idx,
                    const float* __restrict__ dinv1, float* __restrict__ v, int N) {
    int j = blockIdx.x * blockDim.x + threadIdx.x;
    if (j >= N) return;
    float s = dinv1[j];
    int lo = row_ptr[j], hi = row_ptr[j + 1];
    for (int e = lo; e < hi; e++) s += dinv1[row_idx[e]];
    v[j] = dinv1[j] * s;
}

// ---------------- Wc = W1 @ fc1_W (fp32), store bf16 transposed; bc = b1@fc1_W + fc1_b ----------------
__global__ __launch_bounds__(128) void k_wc(const float* __restrict__ W1, const float* __restrict__ fc1W,
                                            const float* __restrict__ b1, const float* __restrict__ fc1b,
                                            ushort* __restrict__ Wct, float* __restrict__ bc) {
    int n = blockIdx.x, k = threadIdx.x;
    __shared__ float fcol[256];
    fcol[k] = fc1W[k * 128 + n];
    fcol[k + 128] = fc1W[(k + 128) * 128 + n];
    __syncthreads();
    float acc = 0.f;
    for (int m = 0; m < 256; m++) acc += W1[k * 256 + m] * fcol[m];
    Wct[n * 128 + k] = f2bf(acc);
    if (k == 0) {
        float a = fc1b[n];
        for (int m = 0; m < 256; m++) a += b1[m] * fcol[m];
        bc[n] = a;
    }
}

// ---------------- aggX[i] = bf16( dinv1[i] * sum_{j in in(i)+self} Xs[j] ) ----------------
// 1 wave per node; lane l owns cols 2l, 2l+1 (one uint).
__global__ __launch_bounds__(256) void k_aggX(const unsigned* __restrict__ Xs2,
                                              const int* __restrict__ col_ptr, const ushort* __restrict__ col_idx,
                                              const float* __restrict__ dinv1,
                                              unsigned* __restrict__ aggX2, int N) {
    int wv = threadIdx.x >> 6, l = threadIdx.x & 63;
    int i = blockIdx.x * 4 + wv;
    if (i >= N) return;
    int lo = col_ptr[i], hi = col_ptr[i + 1];
    unsigned p0 = Xs2[(long)i * 64 + l];          // self loop (Xs pre-scaled by dinv1[src])
    float a0 = bf2f((ushort)(p0 & 0xffff));
    float a1 = bf2f((ushort)(p0 >> 16));
    for (int e = lo; e < hi; e++) {
        int s = col_idx[e];                       // wave-uniform broadcast load
        unsigned p = Xs2[(long)s * 64 + l];
        a0 += bf2f((ushort)(p & 0xffff));
        a1 += bf2f((ushort)(p >> 16));
    }
    float d = dinv1[i];
    aggX2[(long)i * 64 + l] = (unsigned)f2bf(d * a0) | ((unsigned)f2bf(d * a1) << 16);
}

// ---------------- bf16 MFMA GEMM: abst(bf16) = tanh(aggX @ Wc + bc) ----------------
template <int KTOT, int NC>
__global__ __launch_bounds__(256) void k_gemm_mfma(
    const ushort* __restrict__ A, const ushort* __restrict__ Bt,
    const float* __restrict__ bias, ushort* __restrict__ Cout, int N)
{
    constexpr int NT = NC / 16;
    __shared__ ushort Bs[NC * KTOT];
    int t = threadIdx.x;
    constexpr int CPR = KTOT / 8;
    for (int idx = t; idx < NC * CPR; idx += 256) {
        int n = idx / CPR, c = idx % CPR;
        int cs = c ^ (n & 15);                    // XOR swizzle: conflict-free ds_read_b128
        *(short8*)&Bs[n * KTOT + cs * 8] = *(const short8*)&Bt[(long)n * KTOT + c * 8];
    }
    __syncthreads();

    int wave = t >> 6, lane = t & 63;
    int quad = lane >> 4, l15 = lane & 15;
    int arow = blockIdx.x * 64 + wave * 16 + l15;
    long aoff_row = (long)min(arow, N - 1) * KTOT;

    floatx4 acc[NT];
#pragma unroll
    for (int tt = 0; tt < NT; tt++) acc[tt] = {0.f, 0.f, 0.f, 0.f};

    for (int k0 = 0; k0 < KTOT; k0 += 32) {
        short8 af = *(const short8*)&A[aoff_row + k0 + quad * 8];
#pragma unroll
        for (int tt = 0; tt < NT; tt++) {
            int n = tt * 16 + l15;
            int cix = ((k0 >> 3) + quad) ^ (n & 15);
            short8 bf = *(const short8*)&Bs[n * KTOT + cix * 8];
            acc[tt] = __builtin_amdgcn_mfma_f32_16x16x32_bf16(af, bf, acc[tt], 0, 0, 0);
        }
    }

    int rbase = blockIdx.x * 64 + wave * 16 + quad * 4;
#pragma unroll
    for (int r = 0; r < 4; r++) {
        int rowi = rbase + r;
        if (rowi < N) {
#pragma unroll
            for (int tt = 0; tt < NT; tt++) {
                int c = tt * 16 + l15;
                Cout[(long)rowi * NC + c] = f2bf(tanhf(acc[tt][r] + bias[c]));
            }
        }
    }
}

// ---------------- fc2 + softmax + z = dinv2*S (abst is bf16) ----------------
__global__ __launch_bounds__(256) void k_mlp2(const unsigned* __restrict__ ab2, const float* __restrict__ W2,
                                              const float* __restrict__ b2, const float* __restrict__ dinv2,
                                              float* __restrict__ Sm, ushort* __restrict__ z, int N) {
    __shared__ float Ws[D2 * KCL];
    __shared__ float ar[8][132];
    int t = threadIdx.x;
    for (int i = t; i < D2 * KCL; i += 256) Ws[i] = W2[i];
    int g = t >> 5, l = t & 31;
    for (int i0 = blockIdx.x * 8; i0 < N; i0 += gridDim.x * 8) {
        int m = min(8, N - i0);
        __syncthreads();
        for (int idx = t; idx < m * 64; idx += 256) {
            unsigned p = ab2[(long)i0 * 64 + idx];
            int gg = idx >> 6, cc = (idx & 63) * 2;
            ar[gg][cc]     = bf2f((ushort)(p & 0xffff));
            ar[gg][cc + 1] = bf2f((ushort)(p >> 16));
        }
        __syncthreads();
        if (g < m) {
            int node = i0 + g;
            float logit = b2[l];
#pragma unroll 16
            for (int k = 0; k < 128; k++) logit += ar[g][k] * Ws[k * 32 + l];
            float mx = logit;
#pragma unroll
            for (int mask = 16; mask >= 1; mask >>= 1) mx = fmaxf(mx, __shfl_xor(mx, mask, 32));
            float ex = __expf(logit - mx);
            float sum = ex;
#pragma unroll
            for (int mask = 16; mask >= 1; mask >>= 1) sum += __shfl_xor(sum, mask, 32);
            float sv = ex / sum;
            Sm[(long)node * KCL + l] = sv;
            z[(long)node * KCL + l] = f2bf(dinv2[node] * sv);
        }
    }
}

// ---------------- LS[i] = S[i] - dinv2[i] * sum_{c in out(i)} z[c]  (z bf16) ----------------
__global__ __launch_bounds__(256) void k_LS(const float* __restrict__ Sm, const ushort* __restrict__ z,
                                            const int* __restrict__ row_ptr, const ushort* __restrict__ row_idx,
                                            const float* __restrict__ dinv2,
                                            float* __restrict__ LS, int N) {
    int g = threadIdx.x >> 5;
    int l = threadIdx.x & 31;
    int i = blockIdx.x * 8 + g;
    if (i >= N) return;
    int lo = row_ptr[i], hi = row_ptr[i + 1];
    float acc = 0.f;
    for (int e = lo; e < hi; e++) {
        int c = row_idx[e];
        acc += bf2f(z[(long)c * KCL + l]);
    }
    LS[(long)i * KCL + l] = Sm[(long)i * KCL + l] - dinv2[i] * acc;
}

// ---------------- xsum[c] = sum_j v[j] * X[j][c] ----------------
__global__ __launch_bounds__(128) void k_vX(const float* __restrict__ X, const float* __restrict__ v,
                                            float* __restrict__ xsum, int N) {
    int c = threadIdx.x;
    float acc = 0.f;
    for (int j = blockIdx.x; j < N; j += gridDim.x) acc += v[j] * X[(long)j * FIN + c];
    atomicAdd(&xsum[c], acc);
}

// ---------------- new_adj = S^T @ LS  (32x32) ----------------
__global__ __launch_bounds__(256) void k_newadj(const float* __restrict__ S, const float* __restrict__ LS,
                                                float* __restrict__ newadj, int N) {
    __shared__ float Ss[8][32], Ls[8][32];
    int t = threadIdx.x;
    int l = t & 31, k0 = t >> 5;
    float acc[4] = {0.f, 0.f, 0.f, 0.f};
    for (int i0 = blockIdx.x * 8; i0 < N; i0 += gridDim.x * 8) {
        int m = min(8, N - i0);
        if (t < m * 32) {
            Ss[t >> 5][t & 31] = S[(long)i0 * KCL + t];
            Ls[t >> 5][t & 31] = LS[(long)i0 * KCL + t];
        }
        __syncthreads();
        for (int n = 0; n < m; n++) {
            float lv = Ls[n][l];
#pragma unroll
            for (int j = 0; j < 4; j++) acc[j] += Ss[n][k0 + 8 * j] * lv;
        }
        __syncthreads();
    }
#pragma unroll
    for (int j = 0; j < 4; j++) atomicAdd(&newadj[(k0 + 8 * j) * 32 + l], acc[j]);
}

// ---------------- final: embedding GEMV + pos_penalty ----------------
// out[c] = (xsum @ W1[:,c] + N*b1[c]) / 32 ;  out[256] = penalty
__global__ __launch_bounds__(256) void k_final(const float* __restrict__ newadj, const float* __restrict__ xsum,
                                               const float* __restrict__ W1, const float* __restrict__ b1,
                                               float* __restrict__ out, int N) {
    __shared__ float xs[FIN];
    __shared__ float nd[32];
    int t = threadIdx.x;
    if (t < FIN) xs[t] = xsum[t];
    if (t < 32) {
        float rs = 0.f;
        for (int l = 0; l < 32; l++) rs += fabsf(newadj[t * 32 + l]);
        nd[t] = newadj[t * 32 + t] / fmaxf(rs, 1e-12f);
    }
    __syncthreads();
    float acc = (float)N * b1[t];
    for (int k = 0; k < FIN; k++) acc += xs[k] * W1[k * D1 + t];
    out[t] = acc * (1.0f / 32.0f);
    if (t == 0) {
        float p = 0.f;
        for (int j = 0; j < 32; j++) {
            float d = nd[j];
            p += 31.0f * d * d + (d - 1.0f) * (d - 1.0f);
        }
        out[256] = p / 1024.0f;
    }
}

extern "C" void kernel_launch(void* const* d_in, const int* in_sizes, int n_in,
                              void* d_out, int out_size, void* d_ws, size_t ws_size,
                              hipStream_t stream) {
    const float* X     = (const float*)d_in[0];
    const int*   edges = (const int*)d_in[1];
    const float* W1    = (const float*)d_in[2];
    const float* b1    = (const float*)d_in[3];
    const float* fc1_W = (const float*)d_in[4];
    const float* fc1_b = (const float*)d_in[5];
    const float* fc2_W = (const float*)d_in[6];
    const float* fc2_b = (const float*)d_in[7];
    float* out = (float*)d_out;

    int N = in_sizes[0] / FIN;
    int E = in_sizes[1] / 2;
    int NBIN = (N + 255) >> 8;

    char* w = (char*)d_ws;
    auto carve = [&](size_t bytes) -> void* {
        void* p = (void*)w;
        w += (bytes + 255) & ~(size_t)255;
        return p;
    };
    ushort* Xs      = (ushort*)carve((size_t)N * FIN * 2);          // bf16 dinv1*X; aliased by abst
    ushort* aggX    = (ushort*)carve((size_t)N * FIN * 2);          // bf16 aggregated X
    unsigned* binbuf= (unsigned*)carve((size_t)2 * NBIN * CAP * 4); // dead after P2; aliased by LSm
    float* Sm       = (float*)carve((size_t)N * KCL * 4);
    ushort* zm      = (ushort*)carve((size_t)N * KCL * 2);          // bf16 z
    float* dinv1    = (float*)carve((size_t)N * 4);
    float* dinv2    = (float*)carve((size_t)N * 4);
    float* vvec     = (float*)carve((size_t)N * 4);
    int* col_ptr    = (int*)carve((size_t)(N + 1) * 4);
    int* row_ptr    = (int*)carve((size_t)(N + 1) * 4);
    ushort* col_idx = (ushort*)carve((size_t)E * 2);
    ushort* row_idx = (ushort*)carve((size_t)E * 2);
    ushort* Wct     = (ushort*)carve((size_t)FIN * D2 * 2);         // [n][k] bf16 composed weight
    float* bc       = (float*)carve((size_t)D2 * 4);
    float* accum    = (float*)carve((size_t)(1024 + 128 + 512) * 4);
    float* newadj   = accum;
    float* xsum     = accum + 1024;
    int*   gcnt     = (int*)(accum + 1024 + 128);
    ushort* abst = Xs;             // alias: Xs dead after k_aggX/gemm (both N*FIN*2)
    float* LSm  = (float*)binbuf;  // alias: binbuf dead after k_p2

    hipMemsetAsync(accum, 0, (size_t)(1024 + 128 + 512) * 4, stream);

    k_p1<<<dim3(256, 2), 256, 0, stream>>>(edges, E, NBIN, gcnt, binbuf);
    k_p2<<<dim3(NBIN, 2), 256, 0, stream>>>(binbuf, gcnt, N, E, NBIN,
                                            col_ptr, row_ptr, col_idx, row_idx, dinv1, dinv2);
    k_cast<<<(int)(((long)N * FIN / 2 + 255) / 256), 256, 0, stream>>>(X, dinv1, (unsigned*)Xs, (long)N * FIN / 2);
    k_v<<<(N + 255) / 256, 256, 0, stream>>>(row_ptr, row_idx, dinv1, vvec, N);
    k_wc<<<D2, 128, 0, stream>>>(W1, fc1_W, b1, fc1_b, Wct, bc);

    k_aggX<<<(N + 3) / 4, 256, 0, stream>>>((const unsigned*)Xs, col_ptr, col_idx, dinv1,
                                            (unsigned*)aggX, N);
    k_gemm_mfma<FIN, D2><<<(N + 63) / 64, 256, 0, stream>>>(aggX, Wct, bc, abst, N);
    k_mlp2<<<2048, 256, 0, stream>>>((const unsigned*)abst, fc2_W, fc2_b, dinv2, Sm, zm, N);
    k_LS<<<(N + 7) / 8, 256, 0, stream>>>(Sm, zm, row_ptr, row_idx, dinv2, LSm, N);
    k_vX<<<256, 128, 0, stream>>>(X, vvec, xsum, N);
    k_newadj<<<256, 256, 0, stream>>>(Sm, LSm, newadj, N);
    k_final<<<1, 256, 0, stream>>>(newadj, xsum, W1, b1, out, N);
}

// Round 6
// 298.255 us; speedup vs baseline: 1.3126x; 1.3126x over previous
//
#include <hip/hip_runtime.h>
#include <math.h>

#define FIN 128
#define D1  256
#define D2  128
#define KCL 32
#define CAP 8192          // max edges per 256-node bin (avg ~4082, huge headroom)

typedef __attribute__((ext_vector_type(8))) short short8;
typedef __attribute__((ext_vector_type(4))) float floatx4;

__device__ __forceinline__ ushort f2bf(float f) {
    unsigned u = __float_as_uint(f);
    unsigned r = (u + 0x7fffu + ((u >> 16) & 1u)) >> 16;
    return (ushort)r;
}
__device__ __forceinline__ float bf2f(ushort h) {
    return __uint_as_float(((unsigned)h) << 16);
}

// ---------------- P1: bin-scatter edges (dir 0: by dst, dir 1: by src) ----------------
__global__ __launch_bounds__(256) void k_p1(const int* __restrict__ edges, int E, int NBIN,
                                            int* __restrict__ gcnt, unsigned* __restrict__ binbuf) {
    int dir = blockIdx.y;
    __shared__ int h[256], base[256], cur[256];
    int t = threadIdx.x;
    h[t] = 0;
    __syncthreads();
    int chunk = (E + gridDim.x - 1) / gridDim.x;
    int lo = blockIdx.x * chunk, hi = min(lo + chunk, E);
    const int* keys = dir ? edges : edges + E;
    for (int e = lo + t; e < hi; e += 256) atomicAdd(&h[keys[e] >> 8], 1);
    __syncthreads();
    if (t < NBIN) { base[t] = atomicAdd(&gcnt[dir * NBIN + t], h[t]); }
    cur[t] = 0;
    __syncthreads();
    unsigned* bb = binbuf + (size_t)dir * NBIN * CAP;
    for (int e = lo + t; e < hi; e += 256) {
        int r = edges[e], c = edges[E + e];
        int key = dir ? r : c;
        unsigned payload = dir ? ((unsigned)c | ((unsigned)(r & 255) << 16))
                               : ((unsigned)r | ((unsigned)(c & 255) << 16));
        int b = key >> 8;
        int pos = base[b] + atomicAdd(&cur[b], 1);
        if (pos < CAP) bb[(size_t)b * CAP + pos] = payload;
    }
}

// ---------------- P2: per-bin CSR build + degrees + dinv ----------------
__global__ __launch_bounds__(256) void k_p2(const unsigned* __restrict__ binbuf, const int* __restrict__ gcnt,
                                            int N, int E, int NBIN,
                                            int* __restrict__ col_ptr, int* __restrict__ row_ptr,
                                            ushort* __restrict__ col_idx, ushort* __restrict__ row_idx,
                                            float* __restrict__ dinv1, float* __restrict__ dinv2) {
    int d = blockIdx.y, b = blockIdx.x, t = threadIdx.x;
    __shared__ int sc[256], h[256], hx[256], cur[256];
    sc[t] = (t < NBIN) ? gcnt[d * NBIN + t] : 0;
    __syncthreads();
    for (int st = 1; st < 256; st <<= 1) {
        int u = (t >= st) ? sc[t - st] : 0;
        __syncthreads();
        sc[t] += u;
        __syncthreads();
    }
    int cnt_b = gcnt[d * NBIN + b];
    int binbase = sc[b] - cnt_b;
    h[t] = 0;
    __syncthreads();
    const unsigned* bb = binbuf + ((size_t)d * NBIN + b) * CAP;
    int m = min(cnt_b, CAP);
    for (int i = t; i < m; i += 256) atomicAdd(&h[bb[i] >> 16], 1);
    __syncthreads();
    int hv = h[t];
    hx[t] = hv;
    __syncthreads();
    for (int st = 1; st < 256; st <<= 1) {
        int u = (t >= st) ? hx[t - st] : 0;
        __syncthreads();
        hx[t] += u;
        __syncthreads();
    }
    int excl = hx[t] - hv;
    int node = b * 256 + t;
    if (node < N) {
        if (d == 0) {
            dinv1[node] = rsqrtf((float)hv + 1.0f);
            col_ptr[node] = binbase + excl;
            if (node == N - 1) col_ptr[N] = E;
        } else {
            dinv2[node] = hv ? rsqrtf((float)hv) : 0.0f;
            row_ptr[node] = binbase + excl;
            if (node == N - 1) row_ptr[N] = E;
        }
    }
    hx[t] = excl;
    cur[t] = 0;
    __syncthreads();
    ushort* oidx = d ? row_idx : col_idx;
    for (int i = t; i < m; i += 256) {
        unsigned p = bb[i];
        int nl = p >> 16;
        int rk = atomicAdd(&cur[nl], 1);
        oidx[binbase + hx[nl] + rk] = (ushort)(p & 0xffff);
    }
}

// ---------------- v_j = dinv1[j]*(dinv1[j] + sum_{i in out(j)} dinv1[i]) ----------------
__global__ void k_v(const int* __restrict__ row_ptr, const ushort* __restrict__ row_idx,
                    const float* __restrict__ dinv1, float* __restrict__ v, int N) {
    int j = blockIdx.x * blockDim.x + threadIdx.x;
    if (j >= N) return;
    int lo = row_ptr[j], hi = row_ptr[j + 1];
    float s0 = dinv1[j], s1 = 0.f, s2 = 0.f, s3 = 0.f;
    int e = lo;
    for (; e + 4 <= hi; e += 4) {
        int i0 = row_idx[e], i1 = row_idx[e + 1], i2 = row_idx[e + 2], i3 = row_idx[e + 3];
        s0 += dinv1[i0]; s1 += dinv1[i1]; s2 += dinv1[i2]; s3 += dinv1[i3];
    }
    for (; e < hi; e++) s0 += dinv1[row_idx[e]];
    v[j] = dinv1[j] * ((s0 + s1) + (s2 + s3));
}

// ---------------- fused: Xs = bf16(dinv1*X), xsum[c] += v[j]*X[j][c] ----------------
// 256 threads = 4 row-lanes x 64 col-pairs; grid-stride over rows.
__global__ __launch_bounds__(256) void k_prep(const float* __restrict__ X, const float* __restrict__ dinv1,
                                              const float* __restrict__ vvec,
                                              unsigned* __restrict__ Xs2, float* __restrict__ xsum, int N) {
    int t = threadIdx.x;
    int cp = t & 63;        // col-pair (cols 2cp, 2cp+1)
    int rg = t >> 6;        // row group 0..3
    float s0 = 0.f, s1 = 0.f;
    for (int j0 = blockIdx.x * 4; j0 < N; j0 += gridDim.x * 4) {
        int j = j0 + rg;
        if (j < N) {
            float2 x = ((const float2*)X)[(long)j * 64 + cp];
            float d = dinv1[j];
            Xs2[(long)j * 64 + cp] = (unsigned)f2bf(d * x.x) | ((unsigned)f2bf(d * x.y) << 16);
            float v = vvec[j];
            s0 += v * x.x;
            s1 += v * x.y;
        }
    }
    __shared__ float red[256][2];
    red[t][0] = s0; red[t][1] = s1;
    __syncthreads();
    if (rg == 0) {
        float r0 = red[cp][0] + red[64 + cp][0] + red[128 + cp][0] + red[192 + cp][0];
        float r1 = red[cp][1] + red[64 + cp][1] + red[128 + cp][1] + red[192 + cp][1];
        atomicAdd(&xsum[2 * cp], r0);
        atomicAdd(&xsum[2 * cp + 1], r1);
    }
}

// ---------------- Wc = W1 @ fc1_W (fp32), store bf16 transposed; bc = b1@fc1_W + fc1_b ----------------
__global__ __launch_bounds__(128) void k_wc(const float* __restrict__ W1, const float* __restrict__ fc1W,
                                            const float* __restrict__ b1, const float* __restrict__ fc1b,
                                            ushort* __restrict__ Wct, float* __restrict__ bc) {
    int n = blockIdx.x, k = threadIdx.x;
    __shared__ float fcol[256];
    fcol[k] = fc1W[k * 128 + n];
    fcol[k + 128] = fc1W[(k + 128) * 128 + n];
    __syncthreads();
    float acc = 0.f;
    for (int m = 0; m < 256; m++) acc += W1[k * 256 + m] * fcol[m];
    Wct[n * 128 + k] = f2bf(acc);
    if (k == 0) {
        float a = fc1b[n];
        for (int m = 0; m < 256; m++) a += b1[m] * fcol[m];
        bc[n] = a;
    }
}

// ---------------- aggX[i] = bf16( dinv1[i] * sum_{j in in(i)+self} Xs[j] ) ----------------
// 1 wave per node; lane l owns cols 2l, 2l+1. Unroll-by-8: 8 index loads then
// 8 independent gathers in flight — breaks the idx->gather dependent chain.
__global__ __launch_bounds__(256) void k_aggX(const unsigned* __restrict__ Xs2,
                                              const int* __restrict__ col_ptr, const ushort* __restrict__ col_idx,
                                              const float* __restrict__ dinv1,
                                              unsigned* __restrict__ aggX2, int N) {
    int wv = threadIdx.x >> 6, l = threadIdx.x & 63;
    int i = blockIdx.x * 4 + wv;
    if (i >= N) return;
    int lo = col_ptr[i], hi = col_ptr[i + 1];
    unsigned p0 = Xs2[(long)i * 64 + l];          // self loop (Xs pre-scaled by dinv1[src])
    float a0 = bf2f((ushort)(p0 & 0xffff));
    float a1 = bf2f((ushort)(p0 >> 16));
    float b0 = 0.f, b1v = 0.f, c0 = 0.f, c1 = 0.f, d0 = 0.f, d1 = 0.f;
    int e = lo;
    for (; e + 8 <= hi; e += 8) {
        int s0 = col_idx[e + 0], s1 = col_idx[e + 1], s2 = col_idx[e + 2], s3 = col_idx[e + 3];
        int s4 = col_idx[e + 4], s5 = col_idx[e + 5], s6 = col_idx[e + 6], s7 = col_idx[e + 7];
        unsigned q0 = Xs2[(long)s0 * 64 + l];
        unsigned q1 = Xs2[(long)s1 * 64 + l];
        unsigned q2 = Xs2[(long)s2 * 64 + l];
        unsigned q3 = Xs2[(long)s3 * 64 + l];
        unsigned q4 = Xs2[(long)s4 * 64 + l];
        unsigned q5 = Xs2[(long)s5 * 64 + l];
        unsigned q6 = Xs2[(long)s6 * 64 + l];
        unsigned q7 = Xs2[(long)s7 * 64 + l];
        a0 += bf2f((ushort)(q0 & 0xffff)); a1 += bf2f((ushort)(q0 >> 16));
        b0 += bf2f((ushort)(q1 & 0xffff)); b1v += bf2f((ushort)(q1 >> 16));
        c0 += bf2f((ushort)(q2 & 0xffff)); c1 += bf2f((ushort)(q2 >> 16));
        d0 += bf2f((ushort)(q3 & 0xffff)); d1 += bf2f((ushort)(q3 >> 16));
        a0 += bf2f((ushort)(q4 & 0xffff)); a1 += bf2f((ushort)(q4 >> 16));
        b0 += bf2f((ushort)(q5 & 0xffff)); b1v += bf2f((ushort)(q5 >> 16));
        c0 += bf2f((ushort)(q6 & 0xffff)); c1 += bf2f((ushort)(q6 >> 16));
        d0 += bf2f((ushort)(q7 & 0xffff)); d1 += bf2f((ushort)(q7 >> 16));
    }
    for (; e < hi; e++) {
        int s = col_idx[e];
        unsigned q = Xs2[(long)s * 64 + l];
        a0 += bf2f((ushort)(q & 0xffff));
        a1 += bf2f((ushort)(q >> 16));
    }
    a0 = (a0 + b0) + (c0 + d0);
    a1 = (a1 + b1v) + (c1 + d1);
    float d = dinv1[i];
    aggX2[(long)i * 64 + l] = (unsigned)f2bf(d * a0) | ((unsigned)f2bf(d * a1) << 16);
}

// ---------------- bf16 MFMA GEMM: abst(bf16) = tanh(aggX @ Wc + bc) ----------------
template <int KTOT, int NC>
__global__ __launch_bounds__(256) void k_gemm_mfma(
    const ushort* __restrict__ A, const ushort* __restrict__ Bt,
    const float* __restrict__ bias, ushort* __restrict__ Cout, int N)
{
    constexpr int NT = NC / 16;
    __shared__ ushort Bs[NC * KTOT];
    int t = threadIdx.x;
    constexpr int CPR = KTOT / 8;
    for (int idx = t; idx < NC * CPR; idx += 256) {
        int n = idx / CPR, c = idx % CPR;
        int cs = c ^ (n & 15);                    // XOR swizzle: conflict-free ds_read_b128
        *(short8*)&Bs[n * KTOT + cs * 8] = *(const short8*)&Bt[(long)n * KTOT + c * 8];
    }
    __syncthreads();

    int wave = t >> 6, lane = t & 63;
    int quad = lane >> 4, l15 = lane & 15;
    int arow = blockIdx.x * 64 + wave * 16 + l15;
    long aoff_row = (long)min(arow, N - 1) * KTOT;

    floatx4 acc[NT];
#pragma unroll
    for (int tt = 0; tt < NT; tt++) acc[tt] = {0.f, 0.f, 0.f, 0.f};

    for (int k0 = 0; k0 < KTOT; k0 += 32) {
        short8 af = *(const short8*)&A[aoff_row + k0 + quad * 8];
#pragma unroll
        for (int tt = 0; tt < NT; tt++) {
            int n = tt * 16 + l15;
            int cix = ((k0 >> 3) + quad) ^ (n & 15);
            short8 bf = *(const short8*)&Bs[n * KTOT + cix * 8];
            acc[tt] = __builtin_amdgcn_mfma_f32_16x16x32_bf16(af, bf, acc[tt], 0, 0, 0);
        }
    }

    int rbase = blockIdx.x * 64 + wave * 16 + quad * 4;
#pragma unroll
    for (int r = 0; r < 4; r++) {
        int rowi = rbase + r;
        if (rowi < N) {
#pragma unroll
            for (int tt = 0; tt < NT; tt++) {
                int c = tt * 16 + l15;
                Cout[(long)rowi * NC + c] = f2bf(tanhf(acc[tt][r] + bias[c]));
            }
        }
    }
}

// ---------------- fc2 + softmax + z = dinv2*S (abst is bf16) ----------------
__global__ __launch_bounds__(256) void k_mlp2(const unsigned* __restrict__ ab2, const float* __restrict__ W2,
                                              const float* __restrict__ b2, const float* __restrict__ dinv2,
                                              float* __restrict__ Sm, ushort* __restrict__ z, int N) {
    __shared__ float Ws[D2 * KCL];
    __shared__ float ar[8][132];
    int t = threadIdx.x;
    for (int i = t; i < D2 * KCL; i += 256) Ws[i] = W2[i];
    int g = t >> 5, l = t & 31;
    for (int i0 = blockIdx.x * 8; i0 < N; i0 += gridDim.x * 8) {
        int m = min(8, N - i0);
        __syncthreads();
        for (int idx = t; idx < m * 64; idx += 256) {
            unsigned p = ab2[(long)i0 * 64 + idx];
            int gg = idx >> 6, cc = (idx & 63) * 2;
            ar[gg][cc]     = bf2f((ushort)(p & 0xffff));
            ar[gg][cc + 1] = bf2f((ushort)(p >> 16));
        }
        __syncthreads();
        if (g < m) {
            int node = i0 + g;
            float logit = b2[l];
#pragma unroll 16
            for (int k = 0; k < 128; k++) logit += ar[g][k] * Ws[k * 32 + l];
            float mx = logit;
#pragma unroll
            for (int mask = 16; mask >= 1; mask >>= 1) mx = fmaxf(mx, __shfl_xor(mx, mask, 32));
            float ex = __expf(logit - mx);
            float sum = ex;
#pragma unroll
            for (int mask = 16; mask >= 1; mask >>= 1) sum += __shfl_xor(sum, mask, 32);
            float sv = ex / sum;
            Sm[(long)node * KCL + l] = sv;
            z[(long)node * KCL + l] = f2bf(dinv2[node] * sv);
        }
    }
}

// ---------------- LS[i] = S[i] - dinv2[i] * sum_{c in out(i)} z[c]  (z bf16) ----------------
__global__ __launch_bounds__(256) void k_LS(const float* __restrict__ Sm, const ushort* __restrict__ z,
                                            const int* __restrict__ row_ptr, const ushort* __restrict__ row_idx,
                                            const float* __restrict__ dinv2,
                                            float* __restrict__ LS, int N) {
    int g = threadIdx.x >> 5;
    int l = threadIdx.x & 31;
    int i = blockIdx.x * 8 + g;
    if (i >= N) return;
    int lo = row_ptr[i], hi = row_ptr[i + 1];
    float a0 = 0.f, a1 = 0.f, a2 = 0.f, a3 = 0.f;
    int e = lo;
    for (; e + 4 <= hi; e += 4) {
        int c0 = row_idx[e], c1 = row_idx[e + 1], c2 = row_idx[e + 2], c3 = row_idx[e + 3];
        a0 += bf2f(z[(long)c0 * KCL + l]);
        a1 += bf2f(z[(long)c1 * KCL + l]);
        a2 += bf2f(z[(long)c2 * KCL + l]);
        a3 += bf2f(z[(long)c3 * KCL + l]);
    }
    for (; e < hi; e++) a0 += bf2f(z[(long)row_idx[e] * KCL + l]);
    float acc = (a0 + a1) + (a2 + a3);
    LS[(long)i * KCL + l] = Sm[(long)i * KCL + l] - dinv2[i] * acc;
}

// ---------------- new_adj = S^T @ LS  (32x32) ----------------
__global__ __launch_bounds__(256) void k_newadj(const float* __restrict__ S, const float* __restrict__ LS,
                                                float* __restrict__ newadj, int N) {
    __shared__ float Ss[8][32], Ls[8][32];
    int t = threadIdx.x;
    int l = t & 31, k0 = t >> 5;
    float acc[4] = {0.f, 0.f, 0.f, 0.f};
    for (int i0 = blockIdx.x * 8; i0 < N; i0 += gridDim.x * 8) {
        int m = min(8, N - i0);
        if (t < m * 32) {
            Ss[t >> 5][t & 31] = S[(long)i0 * KCL + t];
            Ls[t >> 5][t & 31] = LS[(long)i0 * KCL + t];
        }
        __syncthreads();
        for (int n = 0; n < m; n++) {
            float lv = Ls[n][l];
#pragma unroll
            for (int j = 0; j < 4; j++) acc[j] += Ss[n][k0 + 8 * j] * lv;
        }
        __syncthreads();
    }
#pragma unroll
    for (int j = 0; j < 4; j++) atomicAdd(&newadj[(k0 + 8 * j) * 32 + l], acc[j]);
}

// ---------------- final: embedding GEMV + pos_penalty ----------------
__global__ __launch_bounds__(256) void k_final(const float* __restrict__ newadj, const float* __restrict__ xsum,
                                               const float* __restrict__ W1, const float* __restrict__ b1,
                                               float* __restrict__ out, int N) {
    __shared__ float xs[FIN];
    __shared__ float nd[32];
    int t = threadIdx.x;
    if (t < FIN) xs[t] = xsum[t];
    if (t < 32) {
        float rs = 0.f;
        for (int l = 0; l < 32; l++) rs += fabsf(newadj[t * 32 + l]);
        nd[t] = newadj[t * 32 + t] / fmaxf(rs, 1e-12f);
    }
    __syncthreads();
    float acc = (float)N * b1[t];
    for (int k = 0; k < FIN; k++) acc += xs[k] * W1[k * D1 + t];
    out[t] = acc * (1.0f / 32.0f);
    if (t == 0) {
        float p = 0.f;
        for (int j = 0; j < 32; j++) {
            float d = nd[j];
            p += 31.0f * d * d + (d - 1.0f) * (d - 1.0f);
        }
        out[256] = p / 1024.0f;
    }
}

extern "C" void kernel_launch(void* const* d_in, const int* in_sizes, int n_in,
                              void* d_out, int out_size, void* d_ws, size_t ws_size,
                              hipStream_t stream) {
    const float* X     = (const float*)d_in[0];
    const int*   edges = (const int*)d_in[1];
    const float* W1    = (const float*)d_in[2];
    const float* b1    = (const float*)d_in[3];
    const float* fc1_W = (const float*)d_in[4];
    const float* fc1_b = (const float*)d_in[5];
    const float* fc2_W = (const float*)d_in[6];
    const float* fc2_b = (const float*)d_in[7];
    float* out = (float*)d_out;

    int N = in_sizes[0] / FIN;
    int E = in_sizes[1] / 2;
    int NBIN = (N + 255) >> 8;

    char* w = (char*)d_ws;
    auto carve = [&](size_t bytes) -> void* {
        void* p = (void*)w;
        w += (bytes + 255) & ~(size_t)255;
        return p;
    };
    ushort* Xs      = (ushort*)carve((size_t)N * FIN * 2);          // bf16 dinv1*X; aliased by abst
    ushort* aggX    = (ushort*)carve((size_t)N * FIN * 2);          // bf16 aggregated X
    unsigned* binbuf= (unsigned*)carve((size_t)2 * NBIN * CAP * 4); // dead after P2; aliased by LSm
    float* Sm       = (float*)carve((size_t)N * KCL * 4);
    ushort* zm      = (ushort*)carve((size_t)N * KCL * 2);          // bf16 z
    float* dinv1    = (float*)carve((size_t)N * 4);
    float* dinv2    = (float*)carve((size_t)N * 4);
    float* vvec     = (float*)carve((size_t)N * 4);
    int* col_ptr    = (int*)carve((size_t)(N + 1) * 4);
    int* row_ptr    = (int*)carve((size_t)(N + 1) * 4);
    ushort* col_idx = (ushort*)carve((size_t)E * 2);
    ushort* row_idx = (ushort*)carve((size_t)E * 2);
    ushort* Wct     = (ushort*)carve((size_t)FIN * D2 * 2);         // [n][k] bf16 composed weight
    float* bc       = (float*)carve((size_t)D2 * 4);
    float* accum    = (float*)carve((size_t)(1024 + 128 + 512) * 4);
    float* newadj   = accum;
    float* xsum     = accum + 1024;
    int*   gcnt     = (int*)(accum + 1024 + 128);
    ushort* abst = Xs;             // alias: Xs dead after k_aggX/gemm (both N*FIN*2)
    float* LSm  = (float*)binbuf;  // alias: binbuf dead after k_p2

    hipMemsetAsync(accum, 0, (size_t)(1024 + 128 + 512) * 4, stream);

    k_p1<<<dim3(256, 2), 256, 0, stream>>>(edges, E, NBIN, gcnt, binbuf);
    k_p2<<<dim3(NBIN, 2), 256, 0, stream>>>(binbuf, gcnt, N, E, NBIN,
                                            col_ptr, row_ptr, col_idx, row_idx, dinv1, dinv2);
    k_v<<<(N + 255) / 256, 256, 0, stream>>>(row_ptr, row_idx, dinv1, vvec, N);
    k_wc<<<D2, 128, 0, stream>>>(W1, fc1_W, b1, fc1_b, Wct, bc);
    k_prep<<<256, 256, 0, stream>>>(X, dinv1, vvec, (unsigned*)Xs, xsum, N);

    k_aggX<<<(N + 3) / 4, 256, 0, stream>>>((const unsigned*)Xs, col_ptr, col_idx, dinv1,
                                            (unsigned*)aggX, N);
    k_gemm_mfma<FIN, D2><<<(N + 63) / 64, 256, 0, stream>>>(aggX, Wct, bc, abst, N);
    k_mlp2<<<2048, 256, 0, stream>>>((const unsigned*)abst, fc2_W, fc2_b, dinv2, Sm, zm, N);
    k_LS<<<(N + 7) / 8, 256, 0, stream>>>(Sm, zm, row_ptr, row_idx, dinv2, LSm, N);
    k_newadj<<<256, 256, 0, stream>>>(Sm, LSm, newadj, N);
    k_final<<<1, 256, 0, stream>>>(newadj, xsum, W1, b1, out, N);
}